// Round 3
// baseline (244.904 us; speedup 1.0000x reference)
//
#include <hip/hip_runtime.h>
#include <hip/hip_bf16.h>

typedef unsigned short u16;
typedef __attribute__((ext_vector_type(8))) __bf16 bf16x8;
typedef __attribute__((ext_vector_type(4))) float f32x4;

__device__ __forceinline__ u16 f2bf(float f) {
    unsigned u = __builtin_bit_cast(unsigned, f);
    u += 0x7FFFu + ((u >> 16) & 1u);
    return (u16)(u >> 16);
}
__device__ __forceinline__ float bf2f(u16 v) {
    unsigned u = ((unsigned)v) << 16;
    return __builtin_bit_cast(float, u);
}

// ---------------------------------------------------------------- prep -----
// blocks 0..255: transpose x -> xt (B,HW,C) bf16.
// block 256: We1 reorder -> Ae[ch][p][ci] bf16; BN fold -> eparams; W -> Wb bf16.
__global__ __launch_bounds__(256) void prep_kernel(
    const float* __restrict__ x,
    const float* __restrict__ Wq, const float* __restrict__ Wk, const float* __restrict__ Wv,
    const float* __restrict__ We1, const float* __restrict__ be1,
    const float* __restrict__ bn_w, const float* __restrict__ bn_b,
    const float* __restrict__ bn_mean, const float* __restrict__ bn_var,
    const float* __restrict__ We2,
    u16* __restrict__ xt, u16* __restrict__ Wb, u16* __restrict__ Ae,
    float* __restrict__ eparams)
{
    const int t = threadIdx.x;
    if (blockIdx.x == 256) {
        for (int e = t; e < 18432; e += 256) {
            int ch = e / 576, rem = e - ch * 576;
            int p = rem >> 6, ci = rem & 63;
            Ae[e] = f2bf(We1[ch * 576 + ci * 9 + p]);
        }
        for (int e = t; e < 4096; e += 256) {
            Wb[e]        = f2bf(Wq[e]);
            Wb[4096 + e] = f2bf(Wk[e]);
            Wb[8192 + e] = f2bf(Wv[e]);
        }
        if (t < 32) {
            float sc = bn_w[t] * rsqrtf(bn_var[t] + 1e-5f);
            eparams[t]      = sc;
            eparams[32 + t] = (be1[t] - bn_mean[t]) * sc + bn_b[t];
            eparams[64 + t] = We2[t];
        }
        return;
    }
    __shared__ float xs[64][65];
    const int b = blockIdx.x >> 6;
    const int n0 = (blockIdx.x & 63) << 6;
    for (int i = 0; i < 16; ++i) {
        int lin = t + i * 256;
        xs[lin >> 6][lin & 63] = x[(size_t)(b * 64 + (lin >> 6)) * 4096 + n0 + (lin & 63)];
    }
    __syncthreads();
    const int n = t >> 2, chk = t & 3;
    u16 tmp[16];
#pragma unroll
    for (int j = 0; j < 16; ++j) tmp[j] = f2bf(xs[chk * 16 + j][n]);
    u16* dst = xt + ((size_t)(b * 4096 + n0 + n)) * 64 + chk * 16;
    *reinterpret_cast<uint4*>(dst)     = *reinterpret_cast<const uint4*>(&tmp[0]);
    *reinterpret_cast<uint4*>(dst + 8) = *reinterpret_cast<const uint4*>(&tmp[8]);
}

// ------------------------------------------------------------ qkv + edge ---
// grid 512: bid<256 -> qkv-MFMA (64 px/block); bid>=256 -> edge-MFMA (one row/block)
__global__ __launch_bounds__(256) void qkv_edge_kernel(
    const u16* __restrict__ xt, const u16* __restrict__ Wb,
    const float* __restrict__ bq, const float* __restrict__ bk, const float* __restrict__ bv,
    const u16* __restrict__ Ae, const float* __restrict__ eparams,
    const float* __restrict__ be2, const float* __restrict__ beta,
    u16* __restrict__ Qt, u16* __restrict__ Kt, u16* __restrict__ Vm,
    float* __restrict__ wkey)
{
    __shared__ __align__(16) u16 sm[18432];
    const int t = threadIdx.x;
    const int wv = t >> 6, lane = t & 63;
    const int quad = lane >> 4, l15 = lane & 15;

    if (blockIdx.x < 256) {
        // ---------------- qkv ----------------
        const int b = blockIdx.x >> 6;
        const int n0 = (blockIdx.x & 63) << 6;
        const int px = n0 + wv * 16 + l15;

        bf16x8 bx[2];
#pragma unroll
        for (int h = 0; h < 2; ++h)
            bx[h] = __builtin_bit_cast(bf16x8, *reinterpret_cast<const uint4*>(
                xt + ((size_t)(b * 4096 + px)) * 64 + h * 32 + quad * 8));

        f32x4 d[3][4];
#pragma unroll
        for (int m = 0; m < 3; ++m)
#pragma unroll
            for (int mt = 0; mt < 4; ++mt) d[m][mt] = (f32x4){0.f, 0.f, 0.f, 0.f};

#pragma unroll
        for (int h = 0; h < 2; ++h)
#pragma unroll
            for (int m = 0; m < 3; ++m)
#pragma unroll
                for (int mt = 0; mt < 4; ++mt) {
                    bf16x8 af = __builtin_bit_cast(bf16x8, *reinterpret_cast<const uint4*>(
                        Wb + m * 4096 + (mt * 16 + l15) * 64 + h * 32 + quad * 8));
                    d[m][mt] = __builtin_amdgcn_mfma_f32_16x16x32_bf16(af, bx[h], d[m][mt], 0, 0, 0);
                }

        const float* bias[3] = {bq, bk, bv};
#pragma unroll
        for (int m = 0; m < 3; ++m)
#pragma unroll
            for (int mt = 0; mt < 4; ++mt) {
                float4 bi = *reinterpret_cast<const float4*>(bias[m] + mt * 16 + quad * 4);
                d[m][mt][0] += bi.x; d[m][mt][1] += bi.y; d[m][mt][2] += bi.z; d[m][mt][3] += bi.w;
            }

        // Q, K: row=oc (quad*4+r), col=px (l15); pack 4 consecutive oc
#pragma unroll
        for (int m = 0; m < 2; ++m) {
            u16* dst = (m == 0 ? Qt : Kt) + ((size_t)(b * 4096 + px)) * 64;
#pragma unroll
            for (int mt = 0; mt < 4; ++mt) {
                uint2 pk;
                pk.x = (unsigned)f2bf(d[m][mt][0]) | ((unsigned)f2bf(d[m][mt][1]) << 16);
                pk.y = (unsigned)f2bf(d[m][mt][2]) | ((unsigned)f2bf(d[m][mt][3]) << 16);
                *reinterpret_cast<uint2*>(dst + mt * 16 + quad * 4) = pk;
            }
        }
        // V: through LDS to coalesce (layout [oc][px], stride 72)
        u16* vt = sm;
#pragma unroll
        for (int mt = 0; mt < 4; ++mt)
#pragma unroll
            for (int r = 0; r < 4; ++r)
                vt[(mt * 16 + quad * 4 + r) * 72 + wv * 16 + l15] = f2bf(d[2][mt][r]);
        __syncthreads();
        {
            const int oc = t >> 2, chk = t & 3;
            u16 tmp[16];
#pragma unroll
            for (int j = 0; j < 16; ++j) tmp[j] = vt[oc * 72 + chk * 16 + j];
            u16* dst = Vm + (size_t)(b * 64 + oc) * 4096 + n0 + chk * 16;
            *reinterpret_cast<uint4*>(dst)     = *reinterpret_cast<const uint4*>(&tmp[0]);
            *reinterpret_cast<uint4*>(dst + 8) = *reinterpret_cast<const uint4*>(&tmp[8]);
        }
    } else {
        // ---------------- edge ----------------
        const int eb = blockIdx.x - 256;
        const int b = eb >> 6, h = eb & 63;
        const int w = wv * 16 + l15;

        // stage Ae (36 KB)
#pragma unroll
        for (int i = 0; i < 9; ++i) {
            int lin = (t + i * 256) * 8;
            *reinterpret_cast<uint4*>(&sm[lin]) = *reinterpret_cast<const uint4*>(&Ae[lin]);
        }
        __syncthreads();

        f32x4 e[2];
        e[0] = (f32x4){0.f, 0.f, 0.f, 0.f};
        e[1] = (f32x4){0.f, 0.f, 0.f, 0.f};
#pragma unroll
        for (int p = 0; p < 9; ++p) {
            const int kh = p / 3, kw = p - kh * 3;
            const int hs = h + kh - 1, ws_ = w + kw - 1;
            const bool valid = ((unsigned)hs < 64u) && ((unsigned)ws_ < 64u);
            const u16* bp = xt + ((size_t)(b * 4096) + hs * 64 + ws_) * 64;
#pragma unroll
            for (int half = 0; half < 2; ++half) {
                uint4 bvu = {0u, 0u, 0u, 0u};
                if (valid) bvu = *reinterpret_cast<const uint4*>(bp + half * 32 + quad * 8);
                bf16x8 bf = __builtin_bit_cast(bf16x8, bvu);
#pragma unroll
                for (int mt = 0; mt < 2; ++mt) {
                    bf16x8 af = *reinterpret_cast<const bf16x8*>(
                        &sm[(mt * 16 + l15) * 576 + (p * 2 + half) * 32 + quad * 8]);
                    e[mt] = __builtin_amdgcn_mfma_f32_16x16x32_bf16(af, bf, e[mt], 0, 0, 0);
                }
            }
        }
        // epilogue: ch = mt*16+quad*4+r, px col = l15 (but e's col = B's row = w)
        float partial = 0.f;
#pragma unroll
        for (int mt = 0; mt < 2; ++mt) {
            float4 sc = *reinterpret_cast<const float4*>(eparams + mt * 16 + quad * 4);
            float4 sh = *reinterpret_cast<const float4*>(eparams + 32 + mt * 16 + quad * 4);
            float4 w2 = *reinterpret_cast<const float4*>(eparams + 64 + mt * 16 + quad * 4);
            partial += fmaxf(e[mt][0] * sc.x + sh.x, 0.f) * w2.x;
            partial += fmaxf(e[mt][1] * sc.y + sh.y, 0.f) * w2.y;
            partial += fmaxf(e[mt][2] * sc.z + sh.z, 0.f) * w2.z;
            partial += fmaxf(e[mt][3] * sc.w + sh.w, 0.f) * w2.w;
        }
        partial += __shfl_xor(partial, 16);
        partial += __shfl_xor(partial, 32);
        if (lane < 16) {
            float s = partial + be2[0];
            float sg = 1.f / (1.f + __expf(-s));
            wkey[(size_t)b * 4096 + h * 64 + wv * 16 + lane] = 1.f + beta[0] * sg;
        }
    }
}

// ------------------------------------------------------------- attention ---
// grid 512 = 128 q-blocks (128 rows) x 4 k-splits; 512 thr = 8 waves x 16 q rows.
// 2 blocks/CU (16 waves/CU). S^T = K*Q^T, fixed-offset softmax, P via wave-local
// LDS, O += P*V^T, all operands direct from global. No __syncthreads in k-loop.
__global__ __launch_bounds__(512, 4) void attn_kernel(
    const u16* __restrict__ Qt, const u16* __restrict__ Kt,
    const u16* __restrict__ Vm, const float* __restrict__ wkey,
    u16* __restrict__ O_part, float* __restrict__ l_part)
{
    __shared__ __align__(16) u16 p_s_all[8 * 16 * 68];
    const int t = threadIdx.x;
    const int qi = blockIdx.x >> 2;        // 0..127
    const int split = blockIdx.x & 3;
    const int b = qi >> 5;
    const int n0 = (qi & 31) << 7;         // 128 q rows per block
    const int wv = t >> 6, lane = t & 63;
    const int quad = lane >> 4, l15 = lane & 15;
    u16* p_s = p_s_all + wv * (16 * 68);

    const u16* Qb = Qt + (size_t)b * 4096 * 64;
    const u16* Kb = Kt + (size_t)b * 4096 * 64;
    const u16* Vb = Vm + (size_t)b * 64 * 4096;
    const float* wb = wkey + (size_t)b * 4096;

    bf16x8 qf[2];
#pragma unroll
    for (int h = 0; h < 2; ++h)
        qf[h] = __builtin_bit_cast(bf16x8, *reinterpret_cast<const uint4*>(
            Qb + (size_t)(n0 + wv * 16 + l15) * 64 + h * 32 + quad * 8));

    const int kt0 = split * 16;
    uint4 kf[4][2];
    float4 wf[4];
#pragma unroll
    for (int mt = 0; mt < 4; ++mt) {
#pragma unroll
        for (int h = 0; h < 2; ++h)
            kf[mt][h] = *reinterpret_cast<const uint4*>(
                Kb + (size_t)(kt0 * 64 + mt * 16 + l15) * 64 + h * 32 + quad * 8);
        wf[mt] = *reinterpret_cast<const float4*>(wb + kt0 * 64 + mt * 16 + quad * 4);
    }

    f32x4 o[4];
#pragma unroll
    for (int f = 0; f < 4; ++f) o[f] = (f32x4){0.f, 0.f, 0.f, 0.f};
    float l_acc = 0.f;

    for (int kt = kt0; kt < kt0 + 16; ++kt) {
        uint4 vf[4][2];
#pragma unroll
        for (int f = 0; f < 4; ++f)
#pragma unroll
            for (int h = 0; h < 2; ++h)
                vf[f][h] = *reinterpret_cast<const uint4*>(
                    Vb + (size_t)(f * 16 + l15) * 4096 + kt * 64 + h * 32 + quad * 8);

        f32x4 s[4];
#pragma unroll
        for (int mt = 0; mt < 4; ++mt) {
            f32x4 a = (f32x4){0.f, 0.f, 0.f, 0.f};
            a = __builtin_amdgcn_mfma_f32_16x16x32_bf16(
                    __builtin_bit_cast(bf16x8, kf[mt][0]), qf[0], a, 0, 0, 0);
            a = __builtin_amdgcn_mfma_f32_16x16x32_bf16(
                    __builtin_bit_cast(bf16x8, kf[mt][1]), qf[1], a, 0, 0, 0);
            s[mt] = a;
        }

        const int ktn = (kt + 1 < kt0 + 16) ? kt + 1 : kt0;
#pragma unroll
        for (int mt = 0; mt < 4; ++mt)
#pragma unroll
            for (int h = 0; h < 2; ++h)
                kf[mt][h] = *reinterpret_cast<const uint4*>(
                    Kb + (size_t)(ktn * 64 + mt * 16 + l15) * 64 + h * 32 + quad * 8);

#pragma unroll
        for (int mt = 0; mt < 4; ++mt) {
            u16 pk[4];
#pragma unroll
            for (int r = 0; r < 4; ++r) {
                float p = __expf(s[mt][r] - 12.0f) *
                          reinterpret_cast<const float*>(&wf[mt])[r];
                l_acc += p;
                pk[r] = f2bf(p);
            }
            uint2 packed;
            packed.x = (unsigned)pk[0] | ((unsigned)pk[1] << 16);
            packed.y = (unsigned)pk[2] | ((unsigned)pk[3] << 16);
            *reinterpret_cast<uint2*>(&p_s[l15 * 68 + mt * 16 + quad * 4]) = packed;
        }

#pragma unroll
        for (int mt = 0; mt < 4; ++mt)
            wf[mt] = *reinterpret_cast<const float4*>(wb + ktn * 64 + mt * 16 + quad * 4);

        bf16x8 pa[2];
#pragma unroll
        for (int h = 0; h < 2; ++h) {
            uint2 lo = *reinterpret_cast<const uint2*>(&p_s[l15 * 68 + h * 32 + quad * 8]);
            uint2 hi = *reinterpret_cast<const uint2*>(&p_s[l15 * 68 + h * 32 + quad * 8 + 4]);
            uint4 c4; c4.x = lo.x; c4.y = lo.y; c4.z = hi.x; c4.w = hi.y;
            pa[h] = __builtin_bit_cast(bf16x8, c4);
        }

#pragma unroll
        for (int f = 0; f < 4; ++f) {
            o[f] = __builtin_amdgcn_mfma_f32_16x16x32_bf16(
                pa[0], __builtin_bit_cast(bf16x8, vf[f][0]), o[f], 0, 0, 0);
            o[f] = __builtin_amdgcn_mfma_f32_16x16x32_bf16(
                pa[1], __builtin_bit_cast(bf16x8, vf[f][1]), o[f], 0, 0, 0);
        }
    }

    const size_t pbase = ((size_t)qi * 4 + split) * 128;
    float v = l_acc;
    v += __shfl_xor(v, 16);
    v += __shfl_xor(v, 32);
    if (lane < 16) l_part[pbase + wv * 16 + lane] = v;
#pragma unroll
    for (int f = 0; f < 4; ++f)
#pragma unroll
        for (int r = 0; r < 4; ++r)
            O_part[(pbase + wv * 16 + quad * 4 + r) * 64 + f * 16 + l15] = f2bf(o[f][r]);
}

// ---------------------------------------------------------------- combine --
__global__ __launch_bounds__(256) void combine_kernel(
    const u16* __restrict__ O_part, const float* __restrict__ l_part,
    const float* __restrict__ x, const float* __restrict__ g_gamma,
    float* __restrict__ out)
{
    __shared__ float ot[64 * 67];
    __shared__ float ls[64];
    const int t = threadIdx.x;
    const int b = blockIdx.x >> 6;
    const int n0c = (blockIdx.x & 63) << 6;
    const int qi = (b << 5) + (n0c >> 7);
    const int row0 = n0c & 127;
    const float gamma = g_gamma[0];

    const int r = t >> 2, seg = t & 3;
    float acc[16];
#pragma unroll
    for (int i = 0; i < 16; ++i) acc[i] = 0.f;
#pragma unroll
    for (int s4 = 0; s4 < 4; ++s4) {
        const u16* p = O_part + ((((size_t)qi * 4 + s4) * 128) + row0 + r) * 64 + seg * 16;
        uint4 u0 = *reinterpret_cast<const uint4*>(p);
        uint4 u1 = *reinterpret_cast<const uint4*>(p + 8);
        const unsigned* uu0 = reinterpret_cast<const unsigned*>(&u0);
        const unsigned* uu1 = reinterpret_cast<const unsigned*>(&u1);
#pragma unroll
        for (int i = 0; i < 4; ++i) {
            acc[2 * i]         += bf2f((u16)(uu0[i] & 0xFFFF));
            acc[2 * i + 1]     += bf2f((u16)(uu0[i] >> 16));
            acc[8 + 2 * i]     += bf2f((u16)(uu1[i] & 0xFFFF));
            acc[8 + 2 * i + 1] += bf2f((u16)(uu1[i] >> 16));
        }
    }
#pragma unroll
    for (int i = 0; i < 16; ++i) ot[r * 67 + seg * 16 + i] = acc[i];
    if (seg == 0) {
        float lsum = 0.f;
#pragma unroll
        for (int s4 = 0; s4 < 4; ++s4)
            lsum += l_part[(((size_t)qi * 4 + s4) * 128) + row0 + r];
        ls[r] = gamma / fmaxf(lsum, 1e-30f);
    }
    __syncthreads();
    const int c = t >> 2, chk = t & 3;
    const size_t gbase = ((size_t)(b * 64 + c)) * 4096 + n0c + chk * 16;
#pragma unroll
    for (int j = 0; j < 4; ++j) {
        float4 xv = *reinterpret_cast<const float4*>(&x[gbase + j * 4]);
        float4 rv;
        int nl = chk * 16 + j * 4;
        rv.x = ot[(nl + 0) * 67 + c] * ls[nl + 0] + xv.x;
        rv.y = ot[(nl + 1) * 67 + c] * ls[nl + 1] + xv.y;
        rv.z = ot[(nl + 2) * 67 + c] * ls[nl + 2] + xv.z;
        rv.w = ot[(nl + 3) * 67 + c] * ls[nl + 3] + xv.w;
        *reinterpret_cast<float4*>(&out[gbase + j * 4]) = rv;
    }
}

// ---------------------------------------------------------------- launch ---
extern "C" void kernel_launch(void* const* d_in, const int* in_sizes, int n_in,
                              void* d_out, int out_size, void* d_ws, size_t ws_size,
                              hipStream_t stream) {
    const float* x      = (const float*)d_in[0];
    const float* Wq     = (const float*)d_in[1];
    const float* bq     = (const float*)d_in[2];
    const float* Wk     = (const float*)d_in[3];
    const float* bk     = (const float*)d_in[4];
    const float* Wv     = (const float*)d_in[5];
    const float* bv     = (const float*)d_in[6];
    const float* We1    = (const float*)d_in[7];
    const float* be1    = (const float*)d_in[8];
    const float* bn_w   = (const float*)d_in[9];
    const float* bn_b   = (const float*)d_in[10];
    const float* bn_mean= (const float*)d_in[11];
    const float* bn_var = (const float*)d_in[12];
    const float* We2    = (const float*)d_in[13];
    const float* be2    = (const float*)d_in[14];
    const float* gamma  = (const float*)d_in[15];
    const float* beta   = (const float*)d_in[16];

    char* ws = (char*)d_ws;
    const size_t KB = 1024, MB = 1024 * 1024;
    u16*   Qt     = (u16*)ws;                          // [0, 2 MB)
    u16*   Kt     = (u16*)(ws + 2 * MB);               // [2, 4 MB)
    u16*   Vm     = (u16*)(ws + 4 * MB);               // [4, 6 MB)
    float* wkey   = (float*)(ws + 6 * MB);             // 64 KB
    float* l_part = (float*)(ws + 6 * MB + 64 * KB);   // 256 KB
    u16*   xt     = (u16*)(ws + 6 * MB + 384 * KB);    // 2 MB   (dead after qkv_edge)
    u16*   Wb     = (u16*)(ws + 8 * MB + 384 * KB);    // 24 KB  (dead after qkv_edge)
    u16*   Ae     = (u16*)(ws + 8 * MB + 448 * KB);    // 36 KB  (dead after qkv_edge)
    float* eparams= (float*)(ws + 8 * MB + 512 * KB);  // 384 B  (dead after qkv_edge)
    u16*   O_part = (u16*)(ws + 6 * MB + 384 * KB);    // 8.39 MB, overlays xt/Wb/Ae/eparams

    float* out = (float*)d_out;

    prep_kernel<<<dim3(257), dim3(256), 0, stream>>>(
        x, Wq, Wk, Wv, We1, be1, bn_w, bn_b, bn_mean, bn_var, We2, xt, Wb, Ae, eparams);
    qkv_edge_kernel<<<dim3(512), dim3(256), 0, stream>>>(
        xt, Wb, bq, bk, bv, Ae, eparams, be2, beta, Qt, Kt, Vm, wkey);
    attn_kernel<<<dim3(512), dim3(512), 0, stream>>>(Qt, Kt, Vm, wkey, O_part, l_part);
    combine_kernel<<<dim3(256), dim3(256), 0, stream>>>(O_part, l_part, x, gamma, out);
}

// Round 4
// 205.832 us; speedup vs baseline: 1.1898x; 1.1898x over previous
//
#include <hip/hip_runtime.h>
#include <hip/hip_bf16.h>

typedef unsigned short u16;
typedef __attribute__((ext_vector_type(8))) __bf16 bf16x8;
typedef __attribute__((ext_vector_type(4))) float f32x4;

__device__ __forceinline__ u16 f2bf(float f) {
    unsigned u = __builtin_bit_cast(unsigned, f);
    u += 0x7FFFu + ((u >> 16) & 1u);
    return (u16)(u >> 16);
}

// ---------------------------------------------------------------- prep -----
// blocks 0..255: transpose x -> xt (B,HW,C) bf16.
// block 256: We1 reorder -> Ae[ch][p][ci] bf16; BN fold -> eparams; W -> Wb bf16.
__global__ __launch_bounds__(256) void prep_kernel(
    const float* __restrict__ x,
    const float* __restrict__ Wq, const float* __restrict__ Wk, const float* __restrict__ Wv,
    const float* __restrict__ We1, const float* __restrict__ be1,
    const float* __restrict__ bn_w, const float* __restrict__ bn_b,
    const float* __restrict__ bn_mean, const float* __restrict__ bn_var,
    const float* __restrict__ We2,
    u16* __restrict__ xt, u16* __restrict__ Wb, u16* __restrict__ Ae,
    float* __restrict__ eparams)
{
    const int t = threadIdx.x;
    if (blockIdx.x == 256) {
        for (int e = t; e < 18432; e += 256) {
            int ch = e / 576, rem = e - ch * 576;
            int p = rem >> 6, ci = rem & 63;
            Ae[e] = f2bf(We1[ch * 576 + ci * 9 + p]);
        }
        for (int e = t; e < 4096; e += 256) {
            Wb[e]        = f2bf(Wq[e]);
            Wb[4096 + e] = f2bf(Wk[e]);
            Wb[8192 + e] = f2bf(Wv[e]);
        }
        if (t < 32) {
            float sc = bn_w[t] * rsqrtf(bn_var[t] + 1e-5f);
            eparams[t]      = sc;
            eparams[32 + t] = (be1[t] - bn_mean[t]) * sc + bn_b[t];
            eparams[64 + t] = We2[t];
        }
        return;
    }
    __shared__ float xs[64][65];
    const int b = blockIdx.x >> 6;
    const int n0 = (blockIdx.x & 63) << 6;
    for (int i = 0; i < 16; ++i) {
        int lin = t + i * 256;
        xs[lin >> 6][lin & 63] = x[(size_t)(b * 64 + (lin >> 6)) * 4096 + n0 + (lin & 63)];
    }
    __syncthreads();
    const int n = t >> 2, chk = t & 3;
    u16 tmp[16];
#pragma unroll
    for (int j = 0; j < 16; ++j) tmp[j] = f2bf(xs[chk * 16 + j][n]);
    u16* dst = xt + ((size_t)(b * 4096 + n0 + n)) * 64 + chk * 16;
    *reinterpret_cast<uint4*>(dst)     = *reinterpret_cast<const uint4*>(&tmp[0]);
    *reinterpret_cast<uint4*>(dst + 8) = *reinterpret_cast<const uint4*>(&tmp[8]);
}

// ------------------------------------------------------------ qkv + edge ---
// grid 512: bid<256 -> qkv-MFMA (64 px/block); bid>=256 -> edge-MFMA (one row/block)
__global__ __launch_bounds__(256) void qkv_edge_kernel(
    const u16* __restrict__ xt, const u16* __restrict__ Wb,
    const float* __restrict__ bq, const float* __restrict__ bk, const float* __restrict__ bv,
    const u16* __restrict__ Ae, const float* __restrict__ eparams,
    const float* __restrict__ be2, const float* __restrict__ beta,
    u16* __restrict__ Qt, u16* __restrict__ Kt, u16* __restrict__ Vm,
    float* __restrict__ wkey)
{
    __shared__ __align__(16) u16 sm[18432];
    const int t = threadIdx.x;
    const int wv = t >> 6, lane = t & 63;
    const int quad = lane >> 4, l15 = lane & 15;

    if (blockIdx.x < 256) {
        // ---------------- qkv ----------------
        const int b = blockIdx.x >> 6;
        const int n0 = (blockIdx.x & 63) << 6;
        const int px = n0 + wv * 16 + l15;

        bf16x8 bx[2];
#pragma unroll
        for (int h = 0; h < 2; ++h)
            bx[h] = __builtin_bit_cast(bf16x8, *reinterpret_cast<const uint4*>(
                xt + ((size_t)(b * 4096 + px)) * 64 + h * 32 + quad * 8));

        f32x4 d[3][4];
#pragma unroll
        for (int m = 0; m < 3; ++m)
#pragma unroll
            for (int mt = 0; mt < 4; ++mt) d[m][mt] = (f32x4){0.f, 0.f, 0.f, 0.f};

#pragma unroll
        for (int h = 0; h < 2; ++h)
#pragma unroll
            for (int m = 0; m < 3; ++m)
#pragma unroll
                for (int mt = 0; mt < 4; ++mt) {
                    bf16x8 af = __builtin_bit_cast(bf16x8, *reinterpret_cast<const uint4*>(
                        Wb + m * 4096 + (mt * 16 + l15) * 64 + h * 32 + quad * 8));
                    d[m][mt] = __builtin_amdgcn_mfma_f32_16x16x32_bf16(af, bx[h], d[m][mt], 0, 0, 0);
                }

        const float* bias[3] = {bq, bk, bv};
#pragma unroll
        for (int m = 0; m < 3; ++m)
#pragma unroll
            for (int mt = 0; mt < 4; ++mt) {
                float4 bi = *reinterpret_cast<const float4*>(bias[m] + mt * 16 + quad * 4);
                d[m][mt][0] += bi.x; d[m][mt][1] += bi.y; d[m][mt][2] += bi.z; d[m][mt][3] += bi.w;
            }

#pragma unroll
        for (int m = 0; m < 2; ++m) {
            u16* dst = (m == 0 ? Qt : Kt) + ((size_t)(b * 4096 + px)) * 64;
#pragma unroll
            for (int mt = 0; mt < 4; ++mt) {
                uint2 pk;
                pk.x = (unsigned)f2bf(d[m][mt][0]) | ((unsigned)f2bf(d[m][mt][1]) << 16);
                pk.y = (unsigned)f2bf(d[m][mt][2]) | ((unsigned)f2bf(d[m][mt][3]) << 16);
                *reinterpret_cast<uint2*>(dst + mt * 16 + quad * 4) = pk;
            }
        }
        u16* vt = sm;
#pragma unroll
        for (int mt = 0; mt < 4; ++mt)
#pragma unroll
            for (int r = 0; r < 4; ++r)
                vt[(mt * 16 + quad * 4 + r) * 72 + wv * 16 + l15] = f2bf(d[2][mt][r]);
        __syncthreads();
        {
            const int oc = t >> 2, chk = t & 3;
            u16 tmp[16];
#pragma unroll
            for (int j = 0; j < 16; ++j) tmp[j] = vt[oc * 72 + chk * 16 + j];
            u16* dst = Vm + (size_t)(b * 64 + oc) * 4096 + n0 + chk * 16;
            *reinterpret_cast<uint4*>(dst)     = *reinterpret_cast<const uint4*>(&tmp[0]);
            *reinterpret_cast<uint4*>(dst + 8) = *reinterpret_cast<const uint4*>(&tmp[8]);
        }
    } else {
        // ---------------- edge ----------------
        const int eb = blockIdx.x - 256;
        const int b = eb >> 6, h = eb & 63;
        const int w = wv * 16 + l15;

#pragma unroll
        for (int i = 0; i < 9; ++i) {
            int lin = (t + i * 256) * 8;
            *reinterpret_cast<uint4*>(&sm[lin]) = *reinterpret_cast<const uint4*>(&Ae[lin]);
        }
        __syncthreads();

        f32x4 e[2];
        e[0] = (f32x4){0.f, 0.f, 0.f, 0.f};
        e[1] = (f32x4){0.f, 0.f, 0.f, 0.f};
#pragma unroll
        for (int p = 0; p < 9; ++p) {
            const int kh = p / 3, kw = p - kh * 3;
            const int hs = h + kh - 1, ws_ = w + kw - 1;
            const bool valid = ((unsigned)hs < 64u) && ((unsigned)ws_ < 64u);
            const u16* bp = xt + ((size_t)(b * 4096) + hs * 64 + ws_) * 64;
#pragma unroll
            for (int half = 0; half < 2; ++half) {
                uint4 bvu = {0u, 0u, 0u, 0u};
                if (valid) bvu = *reinterpret_cast<const uint4*>(bp + half * 32 + quad * 8);
                bf16x8 bf = __builtin_bit_cast(bf16x8, bvu);
#pragma unroll
                for (int mt = 0; mt < 2; ++mt) {
                    bf16x8 af = *reinterpret_cast<const bf16x8*>(
                        &sm[(mt * 16 + l15) * 576 + (p * 2 + half) * 32 + quad * 8]);
                    e[mt] = __builtin_amdgcn_mfma_f32_16x16x32_bf16(af, bf, e[mt], 0, 0, 0);
                }
            }
        }
        float partial = 0.f;
#pragma unroll
        for (int mt = 0; mt < 2; ++mt) {
            float4 sc = *reinterpret_cast<const float4*>(eparams + mt * 16 + quad * 4);
            float4 sh = *reinterpret_cast<const float4*>(eparams + 32 + mt * 16 + quad * 4);
            float4 w2 = *reinterpret_cast<const float4*>(eparams + 64 + mt * 16 + quad * 4);
            partial += fmaxf(e[mt][0] * sc.x + sh.x, 0.f) * w2.x;
            partial += fmaxf(e[mt][1] * sc.y + sh.y, 0.f) * w2.y;
            partial += fmaxf(e[mt][2] * sc.z + sh.z, 0.f) * w2.z;
            partial += fmaxf(e[mt][3] * sc.w + sh.w, 0.f) * w2.w;
        }
        partial += __shfl_xor(partial, 16);
        partial += __shfl_xor(partial, 32);
        if (lane < 16) {
            float s = partial + be2[0];
            float sg = 1.f / (1.f + __expf(-s));
            wkey[(size_t)b * 4096 + h * 64 + wv * 16 + lane] = 1.f + beta[0] * sg;
        }
    }
}

// ------------------------------------------------------------- attention ---
// grid 1024 = 128 q-blocks (128 rows) x 8 k-splits; 256 thr = 4 waves x 32 q rows
// (2 independent 16-row chains per wave for ILP). 4 blocks/CU = 16 waves/CU.
// S^T = K*Q^T, fixed-offset softmax, P via wave-local LDS, O += P*V^T; epilogue
// accumulates into fp32 O_accum/l_accum with fire-and-forget global atomics.
__global__ __launch_bounds__(256, 4) void attn_kernel(
    const u16* __restrict__ Qt, const u16* __restrict__ Kt,
    const u16* __restrict__ Vm, const float* __restrict__ wkey,
    float* __restrict__ O_accum, float* __restrict__ l_accum)
{
    __shared__ __align__(16) u16 p_s_all[4 * 32 * 68];
    const int t = threadIdx.x;
    const int qi = blockIdx.x >> 3;        // 0..127
    const int split = blockIdx.x & 7;
    const int b = qi >> 5;
    const int n0 = (qi & 31) << 7;         // 128 q rows per block
    const int wv = t >> 6, lane = t & 63;
    const int quad = lane >> 4, l15 = lane & 15;
    u16* p_s = p_s_all + wv * (32 * 68);

    const u16* Qb = Qt + (size_t)b * 4096 * 64;
    const u16* Kb = Kt + (size_t)b * 4096 * 64;
    const u16* Vb = Vm + (size_t)b * 64 * 4096;
    const float* wb = wkey + (size_t)b * 4096;

    bf16x8 qf[2][2];
#pragma unroll
    for (int nt = 0; nt < 2; ++nt)
#pragma unroll
        for (int h = 0; h < 2; ++h)
            qf[nt][h] = __builtin_bit_cast(bf16x8, *reinterpret_cast<const uint4*>(
                Qb + (size_t)(n0 + wv * 32 + nt * 16 + l15) * 64 + h * 32 + quad * 8));

    const int kt0 = split * 8;
    uint4 kf[4][2];
    float4 wf[4];
#pragma unroll
    for (int mt = 0; mt < 4; ++mt) {
#pragma unroll
        for (int h = 0; h < 2; ++h)
            kf[mt][h] = *reinterpret_cast<const uint4*>(
                Kb + (size_t)(kt0 * 64 + mt * 16 + l15) * 64 + h * 32 + quad * 8);
        wf[mt] = *reinterpret_cast<const float4*>(wb + kt0 * 64 + mt * 16 + quad * 4);
    }

    f32x4 o[2][4];
#pragma unroll
    for (int m2 = 0; m2 < 2; ++m2)
#pragma unroll
        for (int f = 0; f < 4; ++f) o[m2][f] = (f32x4){0.f, 0.f, 0.f, 0.f};
    float l_acc[2] = {0.f, 0.f};

    for (int kt = kt0; kt < kt0 + 8; ++kt) {
        uint4 vf[4][2];
#pragma unroll
        for (int f = 0; f < 4; ++f)
#pragma unroll
            for (int h = 0; h < 2; ++h)
                vf[f][h] = *reinterpret_cast<const uint4*>(
                    Vb + (size_t)(f * 16 + l15) * 4096 + kt * 64 + h * 32 + quad * 8);

        f32x4 s[4][2];
#pragma unroll
        for (int mt = 0; mt < 4; ++mt)
#pragma unroll
            for (int nt = 0; nt < 2; ++nt) {
                f32x4 a = (f32x4){0.f, 0.f, 0.f, 0.f};
                a = __builtin_amdgcn_mfma_f32_16x16x32_bf16(
                        __builtin_bit_cast(bf16x8, kf[mt][0]), qf[nt][0], a, 0, 0, 0);
                a = __builtin_amdgcn_mfma_f32_16x16x32_bf16(
                        __builtin_bit_cast(bf16x8, kf[mt][1]), qf[nt][1], a, 0, 0, 0);
                s[mt][nt] = a;
            }

        const int ktn = (kt + 1 < kt0 + 8) ? kt + 1 : kt0;
#pragma unroll
        for (int mt = 0; mt < 4; ++mt)
#pragma unroll
            for (int h = 0; h < 2; ++h)
                kf[mt][h] = *reinterpret_cast<const uint4*>(
                    Kb + (size_t)(ktn * 64 + mt * 16 + l15) * 64 + h * 32 + quad * 8);

#pragma unroll
        for (int mt = 0; mt < 4; ++mt)
#pragma unroll
            for (int nt = 0; nt < 2; ++nt) {
                u16 pk[4];
#pragma unroll
                for (int r = 0; r < 4; ++r) {
                    float p = __expf(s[mt][nt][r] - 12.0f) *
                              reinterpret_cast<const float*>(&wf[mt])[r];
                    l_acc[nt] += p;
                    pk[r] = f2bf(p);
                }
                uint2 packed;
                packed.x = (unsigned)pk[0] | ((unsigned)pk[1] << 16);
                packed.y = (unsigned)pk[2] | ((unsigned)pk[3] << 16);
                *reinterpret_cast<uint2*>(
                    &p_s[(nt * 16 + l15) * 68 + mt * 16 + quad * 4]) = packed;
            }

#pragma unroll
        for (int mt = 0; mt < 4; ++mt)
            wf[mt] = *reinterpret_cast<const float4*>(wb + ktn * 64 + mt * 16 + quad * 4);

        bf16x8 pa[2][2];
#pragma unroll
        for (int m2 = 0; m2 < 2; ++m2)
#pragma unroll
            for (int h = 0; h < 2; ++h) {
                uint2 lo = *reinterpret_cast<const uint2*>(
                    &p_s[(m2 * 16 + l15) * 68 + h * 32 + quad * 8]);
                uint2 hi = *reinterpret_cast<const uint2*>(
                    &p_s[(m2 * 16 + l15) * 68 + h * 32 + quad * 8 + 4]);
                uint4 c4; c4.x = lo.x; c4.y = lo.y; c4.z = hi.x; c4.w = hi.y;
                pa[m2][h] = __builtin_bit_cast(bf16x8, c4);
            }

#pragma unroll
        for (int m2 = 0; m2 < 2; ++m2)
#pragma unroll
            for (int f = 0; f < 4; ++f) {
                o[m2][f] = __builtin_amdgcn_mfma_f32_16x16x32_bf16(
                    pa[m2][0], __builtin_bit_cast(bf16x8, vf[f][0]), o[m2][f], 0, 0, 0);
                o[m2][f] = __builtin_amdgcn_mfma_f32_16x16x32_bf16(
                    pa[m2][1], __builtin_bit_cast(bf16x8, vf[f][1]), o[m2][f], 0, 0, 0);
            }
    }

    // epilogue: fire-and-forget fp32 atomics
#pragma unroll
    for (int nt = 0; nt < 2; ++nt) {
        float v = l_acc[nt];
        v += __shfl_xor(v, 16);
        v += __shfl_xor(v, 32);
        if (lane < 16)
            atomicAdd(&l_accum[(size_t)b * 4096 + n0 + wv * 32 + nt * 16 + lane], v);
    }
#pragma unroll
    for (int m2 = 0; m2 < 2; ++m2)
#pragma unroll
        for (int f = 0; f < 4; ++f)
#pragma unroll
            for (int r = 0; r < 4; ++r)
                atomicAdd(&O_accum[((size_t)(b * 4096 + n0 + wv * 32 + m2 * 16 + quad * 4 + r)) * 64
                                   + f * 16 + l15], o[m2][f][r]);
}

// ---------------------------------------------------------------- combine --
// grid 256: normalize by l, gamma*O + x, transpose (b,n,c)->(b,c,n)
__global__ __launch_bounds__(256) void combine_kernel(
    const float* __restrict__ O_accum, const float* __restrict__ l_accum,
    const float* __restrict__ x, const float* __restrict__ g_gamma,
    float* __restrict__ out)
{
    __shared__ float ot[64 * 67];
    __shared__ float ls[64];
    const int t = threadIdx.x;
    const int b = blockIdx.x >> 6;
    const int n0c = (blockIdx.x & 63) << 6;
    const float gamma = g_gamma[0];

    const int r = t >> 2, seg = t & 3;
    const float* p = O_accum + ((size_t)(b * 4096 + n0c + r)) * 64 + seg * 16;
#pragma unroll
    for (int q4 = 0; q4 < 4; ++q4) {
        float4 v = *reinterpret_cast<const float4*>(p + q4 * 4);
        ot[r * 67 + seg * 16 + q4 * 4 + 0] = v.x;
        ot[r * 67 + seg * 16 + q4 * 4 + 1] = v.y;
        ot[r * 67 + seg * 16 + q4 * 4 + 2] = v.z;
        ot[r * 67 + seg * 16 + q4 * 4 + 3] = v.w;
    }
    if (seg == 0)
        ls[r] = gamma / fmaxf(l_accum[(size_t)b * 4096 + n0c + r], 1e-30f);
    __syncthreads();
    const int c = t >> 2, chk = t & 3;
    const size_t gbase = ((size_t)(b * 64 + c)) * 4096 + n0c + chk * 16;
#pragma unroll
    for (int j = 0; j < 4; ++j) {
        float4 xv = *reinterpret_cast<const float4*>(&x[gbase + j * 4]);
        float4 rv;
        int nl = chk * 16 + j * 4;
        rv.x = ot[(nl + 0) * 67 + c] * ls[nl + 0] + xv.x;
        rv.y = ot[(nl + 1) * 67 + c] * ls[nl + 1] + xv.y;
        rv.z = ot[(nl + 2) * 67 + c] * ls[nl + 2] + xv.z;
        rv.w = ot[(nl + 3) * 67 + c] * ls[nl + 3] + xv.w;
        *reinterpret_cast<float4*>(&out[gbase + j * 4]) = rv;
    }
}

// ---------------------------------------------------------------- launch ---
extern "C" void kernel_launch(void* const* d_in, const int* in_sizes, int n_in,
                              void* d_out, int out_size, void* d_ws, size_t ws_size,
                              hipStream_t stream) {
    const float* x      = (const float*)d_in[0];
    const float* Wq     = (const float*)d_in[1];
    const float* bq     = (const float*)d_in[2];
    const float* Wk     = (const float*)d_in[3];
    const float* bk     = (const float*)d_in[4];
    const float* Wv     = (const float*)d_in[5];
    const float* bv     = (const float*)d_in[6];
    const float* We1    = (const float*)d_in[7];
    const float* be1    = (const float*)d_in[8];
    const float* bn_w   = (const float*)d_in[9];
    const float* bn_b   = (const float*)d_in[10];
    const float* bn_mean= (const float*)d_in[11];
    const float* bn_var = (const float*)d_in[12];
    const float* We2    = (const float*)d_in[13];
    const float* be2    = (const float*)d_in[14];
    const float* gamma  = (const float*)d_in[15];
    const float* beta   = (const float*)d_in[16];

    char* ws = (char*)d_ws;
    const size_t KB = 1024, MB = 1024 * 1024;
    u16*   Qt      = (u16*)ws;                           // [0, 2 MB)
    u16*   Kt      = (u16*)(ws + 2 * MB);                // [2, 4 MB)
    u16*   Vm      = (u16*)(ws + 4 * MB);                // [4, 6 MB)
    float* wkey    = (float*)(ws + 6 * MB);              // 64 KB
    float* l_accum = (float*)(ws + 6 * MB + 64 * KB);    // 64 KB  (zeroed)
    float* O_accum = (float*)(ws + 6 * MB + 128 * KB);   // 4 MB   (zeroed)
    u16*   xt      = (u16*)(ws + 10 * MB + 128 * KB);    // 2 MB
    u16*   Wb      = (u16*)(ws + 12 * MB + 128 * KB);    // 24 KB
    u16*   Ae      = (u16*)(ws + 12 * MB + 192 * KB);    // 36 KB
    float* eparams = (float*)(ws + 12 * MB + 256 * KB);  // 384 B

    float* out = (float*)d_out;

    hipMemsetAsync(ws + 6 * MB + 64 * KB, 0, 4 * MB + 64 * KB, stream);
    prep_kernel<<<dim3(257), dim3(256), 0, stream>>>(
        x, Wq, Wk, Wv, We1, be1, bn_w, bn_b, bn_mean, bn_var, We2, xt, Wb, Ae, eparams);
    qkv_edge_kernel<<<dim3(512), dim3(256), 0, stream>>>(
        xt, Wb, bq, bk, bv, Ae, eparams, be2, beta, Qt, Kt, Vm, wkey);
    attn_kernel<<<dim3(1024), dim3(256), 0, stream>>>(Qt, Kt, Vm, wkey, O_accum, l_accum);
    combine_kernel<<<dim3(256), dim3(256), 0, stream>>>(O_accum, l_accum, x, gamma, out);
}

// Round 5
// 179.459 us; speedup vs baseline: 1.3647x; 1.1470x over previous
//
#include <hip/hip_runtime.h>
#include <hip/hip_bf16.h>

typedef unsigned short u16;
typedef __attribute__((ext_vector_type(8))) __bf16 bf16x8;
typedef __attribute__((ext_vector_type(4))) float f32x4;

__device__ __forceinline__ u16 f2bf(float f) {
    unsigned u = __builtin_bit_cast(unsigned, f);
    u += 0x7FFFu + ((u >> 16) & 1u);
    return (u16)(u >> 16);
}
__device__ __forceinline__ float bf2f(u16 v) {
    unsigned u = ((unsigned)v) << 16;
    return __builtin_bit_cast(float, u);
}

// ------------------------------------------------------------ qkv + edge ---
// grid 512, self-contained (no prep pass):
//  bid<256:  qkv  — stage x-tile transposed + W(bf16) in LDS, 24 MFMAs
//  bid>=256: edge — stage 3 x-rows (zero-padded) + We1 reorder in LDS, 36 MFMAs
__global__ __launch_bounds__(256) void qkv_edge_kernel(
    const float* __restrict__ x,
    const float* __restrict__ Wq, const float* __restrict__ bq,
    const float* __restrict__ Wk, const float* __restrict__ bk,
    const float* __restrict__ Wv, const float* __restrict__ bv,
    const float* __restrict__ We1, const float* __restrict__ be1,
    const float* __restrict__ bn_w, const float* __restrict__ bn_b,
    const float* __restrict__ bn_mean, const float* __restrict__ bn_var,
    const float* __restrict__ We2, const float* __restrict__ be2,
    const float* __restrict__ beta,
    u16* __restrict__ Qt, u16* __restrict__ Kt, u16* __restrict__ Vm,
    float* __restrict__ wkey)
{
    __shared__ __align__(16) u16 sm[33280];   // 65 KB, partitioned per branch
    const int t = threadIdx.x;
    const int wv = t >> 6, lane = t & 63;
    const int quad = lane >> 4, l15 = lane & 15;

    if (blockIdx.x < 256) {
        // ---------------- qkv ----------------
        u16* Wl   = sm;                 // [3][64][72]  = 13824 u16
        u16* xt_s = sm + 13824;         // [64][66]     =  4224 u16
        u16* vt   = sm + 13824 + 4224;  // [64][72]     =  4608 u16
        const int b = blockIdx.x >> 6;
        const int n0 = (blockIdx.x & 63) << 6;

        const float* Wmat[3] = {Wq, Wk, Wv};
#pragma unroll
        for (int m = 0; m < 3; ++m)
            for (int i = 0; i < 16; ++i) {
                int lin = t + i * 256;
                Wl[(m * 64 + (lin >> 6)) * 72 + (lin & 63)] = f2bf(Wmat[m][lin]);
            }
        for (int i = 0; i < 16; ++i) {
            int lin = t + i * 256;
            int c = lin >> 6, nn = lin & 63;
            xt_s[nn * 66 + c] = f2bf(x[(size_t)(b * 64 + c) * 4096 + n0 + nn]);
        }
        __syncthreads();

        bf16x8 bx[2];
#pragma unroll
        for (int h = 0; h < 2; ++h)
            bx[h] = *reinterpret_cast<const bf16x8*>(
                &xt_s[(wv * 16 + l15) * 66 + h * 32 + quad * 8]);

        f32x4 d[3][4];
#pragma unroll
        for (int m = 0; m < 3; ++m)
#pragma unroll
            for (int mt = 0; mt < 4; ++mt) d[m][mt] = (f32x4){0.f, 0.f, 0.f, 0.f};

#pragma unroll
        for (int h = 0; h < 2; ++h)
#pragma unroll
            for (int m = 0; m < 3; ++m)
#pragma unroll
                for (int mt = 0; mt < 4; ++mt) {
                    bf16x8 af = *reinterpret_cast<const bf16x8*>(
                        &Wl[(m * 64 + mt * 16 + l15) * 72 + h * 32 + quad * 8]);
                    d[m][mt] = __builtin_amdgcn_mfma_f32_16x16x32_bf16(af, bx[h], d[m][mt], 0, 0, 0);
                }

        const float* bias[3] = {bq, bk, bv};
#pragma unroll
        for (int m = 0; m < 3; ++m)
#pragma unroll
            for (int mt = 0; mt < 4; ++mt) {
                float4 bi = *reinterpret_cast<const float4*>(bias[m] + mt * 16 + quad * 4);
                d[m][mt][0] += bi.x; d[m][mt][1] += bi.y; d[m][mt][2] += bi.z; d[m][mt][3] += bi.w;
            }

        const int px = n0 + wv * 16 + l15;
#pragma unroll
        for (int m = 0; m < 2; ++m) {
            u16* dst = (m == 0 ? Qt : Kt) + ((size_t)(b * 4096 + px)) * 64;
#pragma unroll
            for (int mt = 0; mt < 4; ++mt) {
                uint2 pk;
                pk.x = (unsigned)f2bf(d[m][mt][0]) | ((unsigned)f2bf(d[m][mt][1]) << 16);
                pk.y = (unsigned)f2bf(d[m][mt][2]) | ((unsigned)f2bf(d[m][mt][3]) << 16);
                *reinterpret_cast<uint2*>(dst + mt * 16 + quad * 4) = pk;
            }
        }
#pragma unroll
        for (int mt = 0; mt < 4; ++mt)
#pragma unroll
            for (int r = 0; r < 4; ++r)
                vt[(mt * 16 + quad * 4 + r) * 72 + wv * 16 + l15] = f2bf(d[2][mt][r]);
        __syncthreads();
        {
            const int oc = t >> 2, chk = t & 3;
            u16 tmp[16];
#pragma unroll
            for (int j = 0; j < 16; ++j) tmp[j] = vt[oc * 72 + chk * 16 + j];
            u16* dst = Vm + (size_t)(b * 64 + oc) * 4096 + n0 + chk * 16;
            *reinterpret_cast<uint4*>(dst)     = *reinterpret_cast<const uint4*>(&tmp[0]);
            *reinterpret_cast<uint4*>(dst + 8) = *reinterpret_cast<const uint4*>(&tmp[8]);
        }
    } else {
        // ---------------- edge ----------------
        u16* Ae_s = sm;            // [32][584]     = 18688 u16 (row pad vs 576)
        u16* xr_s = sm + 18688;    // [3][66][72]   = 14256 u16 (col 0/65 zero)
        const int eb = blockIdx.x - 256;
        const int b = eb >> 6, h = eb & 63;

        // zero boundary columns (w = -1 and w = 64), ci 0..63
        if (t < 192) {
            int kh = t / 64, rem = t & 63;
            int col = (rem >> 5) * 65, ci2 = (rem & 31) * 2;
            *reinterpret_cast<unsigned*>(&xr_s[(kh * 66 + col) * 72 + ci2]) = 0u;
        }
        // We1 (ch,ci,p) -> Ae_s[ch][p][ci] bf16
#pragma unroll
        for (int i = 0; i < 8; ++i) {
            int pr = t + i * 256;
            int ch = pr >> 6, ci = pr & 63;
            const float* src = We1 + ch * 576 + ci * 9;
#pragma unroll
            for (int p = 0; p < 9; ++p)
                Ae_s[ch * 584 + p * 64 + ci] = f2bf(src[p]);
        }
        // x rows h-1..h+1 -> xr_s[kh][w+1][ci] bf16 (zeros when out of range)
#pragma unroll
        for (int i = 0; i < 48; ++i) {
            int e = t + i * 256;
            int kh = e >> 12, rem = e & 4095;
            int ci = rem >> 6, w = rem & 63;
            int hs = h + kh - 1;
            float v = 0.f;
            if ((unsigned)hs < 64u)
                v = x[((size_t)(b * 64 + ci) * 64 + hs) * 64 + w];
            xr_s[(kh * 66 + w + 1) * 72 + ci] = f2bf(v);
        }
        __syncthreads();

        f32x4 e[2];
        e[0] = (f32x4){0.f, 0.f, 0.f, 0.f};
        e[1] = (f32x4){0.f, 0.f, 0.f, 0.f};
#pragma unroll
        for (int p = 0; p < 9; ++p) {
            const int kh = p / 3, kw = p - kh * 3;
#pragma unroll
            for (int half = 0; half < 2; ++half) {
                bf16x8 bfr = *reinterpret_cast<const bf16x8*>(
                    &xr_s[(kh * 66 + wv * 16 + l15 + kw) * 72 + half * 32 + quad * 8]);
#pragma unroll
                for (int mt = 0; mt < 2; ++mt) {
                    bf16x8 af = *reinterpret_cast<const bf16x8*>(
                        &Ae_s[(mt * 16 + l15) * 584 + p * 64 + half * 32 + quad * 8]);
                    e[mt] = __builtin_amdgcn_mfma_f32_16x16x32_bf16(af, bfr, e[mt], 0, 0, 0);
                }
            }
        }
        float partial = 0.f;
#pragma unroll
        for (int mt = 0; mt < 2; ++mt) {
            float4 bw = *reinterpret_cast<const float4*>(bn_w    + mt * 16 + quad * 4);
            float4 bb = *reinterpret_cast<const float4*>(bn_b    + mt * 16 + quad * 4);
            float4 bm = *reinterpret_cast<const float4*>(bn_mean + mt * 16 + quad * 4);
            float4 bv2 = *reinterpret_cast<const float4*>(bn_var + mt * 16 + quad * 4);
            float4 b1 = *reinterpret_cast<const float4*>(be1     + mt * 16 + quad * 4);
            float4 w2 = *reinterpret_cast<const float4*>(We2     + mt * 16 + quad * 4);
            float sc, sh;
            sc = bw.x * rsqrtf(bv2.x + 1e-5f); sh = (b1.x - bm.x) * sc + bb.x;
            partial += fmaxf(e[mt][0] * sc + sh, 0.f) * w2.x;
            sc = bw.y * rsqrtf(bv2.y + 1e-5f); sh = (b1.y - bm.y) * sc + bb.y;
            partial += fmaxf(e[mt][1] * sc + sh, 0.f) * w2.y;
            sc = bw.z * rsqrtf(bv2.z + 1e-5f); sh = (b1.z - bm.z) * sc + bb.z;
            partial += fmaxf(e[mt][2] * sc + sh, 0.f) * w2.z;
            sc = bw.w * rsqrtf(bv2.w + 1e-5f); sh = (b1.w - bm.w) * sc + bb.w;
            partial += fmaxf(e[mt][3] * sc + sh, 0.f) * w2.w;
        }
        partial += __shfl_xor(partial, 16);
        partial += __shfl_xor(partial, 32);
        if (lane < 16) {
            float s = partial + be2[0];
            float sg = 1.f / (1.f + __expf(-s));
            wkey[(size_t)b * 4096 + h * 64 + wv * 16 + lane] = 1.f + beta[0] * sg;
        }
    }
}

// ------------------------------------------------------------- attention ---
// grid 1024 = 256 q-blocks (64 rows) x 4 k-splits; 128 thr = 2 waves x 32 q rows
// (2 independent 16-row chains per wave). 8 blocks/CU = 16 waves/CU.
// S^T = K*Q^T, fixed-offset softmax, P via wave-local LDS, O += P*V^T,
// bf16 O_part epilogue. No __syncthreads in k-loop, no atomics.
__global__ __launch_bounds__(128, 4) void attn_kernel(
    const u16* __restrict__ Qt, const u16* __restrict__ Kt,
    const u16* __restrict__ Vm, const float* __restrict__ wkey,
    u16* __restrict__ O_part, float* __restrict__ l_part)
{
    __shared__ __align__(16) u16 p_s_all[2 * 32 * 68];
    const int t = threadIdx.x;
    const int qi = blockIdx.x >> 2;        // 0..255 (64-row q block)
    const int split = blockIdx.x & 3;
    const int b = qi >> 6;
    const int n0 = (qi & 63) << 6;         // within-batch row base
    const int wv = t >> 6, lane = t & 63;
    const int quad = lane >> 4, l15 = lane & 15;
    u16* p_s = p_s_all + wv * (32 * 68);

    const u16* Qb = Qt + (size_t)b * 4096 * 64;
    const u16* Kb = Kt + (size_t)b * 4096 * 64;
    const u16* Vb = Vm + (size_t)b * 64 * 4096;
    const float* wb = wkey + (size_t)b * 4096;

    bf16x8 qf[2][2];
#pragma unroll
    for (int nt = 0; nt < 2; ++nt)
#pragma unroll
        for (int h = 0; h < 2; ++h)
            qf[nt][h] = __builtin_bit_cast(bf16x8, *reinterpret_cast<const uint4*>(
                Qb + (size_t)(n0 + wv * 32 + nt * 16 + l15) * 64 + h * 32 + quad * 8));

    const int kt0 = split * 16;
    uint4 kf[4][2];
    float4 wf[4];
#pragma unroll
    for (int mt = 0; mt < 4; ++mt) {
#pragma unroll
        for (int h = 0; h < 2; ++h)
            kf[mt][h] = *reinterpret_cast<const uint4*>(
                Kb + (size_t)(kt0 * 64 + mt * 16 + l15) * 64 + h * 32 + quad * 8);
        wf[mt] = *reinterpret_cast<const float4*>(wb + kt0 * 64 + mt * 16 + quad * 4);
    }

    f32x4 o[2][4];
#pragma unroll
    for (int m2 = 0; m2 < 2; ++m2)
#pragma unroll
        for (int f = 0; f < 4; ++f) o[m2][f] = (f32x4){0.f, 0.f, 0.f, 0.f};
    float l_acc[2] = {0.f, 0.f};

    for (int kt = kt0; kt < kt0 + 16; ++kt) {
        uint4 vf[4][2];
#pragma unroll
        for (int f = 0; f < 4; ++f)
#pragma unroll
            for (int h = 0; h < 2; ++h)
                vf[f][h] = *reinterpret_cast<const uint4*>(
                    Vb + (size_t)(f * 16 + l15) * 4096 + kt * 64 + h * 32 + quad * 8);

        f32x4 s[4][2];
#pragma unroll
        for (int mt = 0; mt < 4; ++mt)
#pragma unroll
            for (int nt = 0; nt < 2; ++nt) {
                f32x4 a = (f32x4){0.f, 0.f, 0.f, 0.f};
                a = __builtin_amdgcn_mfma_f32_16x16x32_bf16(
                        __builtin_bit_cast(bf16x8, kf[mt][0]), qf[nt][0], a, 0, 0, 0);
                a = __builtin_amdgcn_mfma_f32_16x16x32_bf16(
                        __builtin_bit_cast(bf16x8, kf[mt][1]), qf[nt][1], a, 0, 0, 0);
                s[mt][nt] = a;
            }

        const int ktn = (kt + 1 < kt0 + 16) ? kt + 1 : kt0;
#pragma unroll
        for (int mt = 0; mt < 4; ++mt)
#pragma unroll
            for (int h = 0; h < 2; ++h)
                kf[mt][h] = *reinterpret_cast<const uint4*>(
                    Kb + (size_t)(ktn * 64 + mt * 16 + l15) * 64 + h * 32 + quad * 8);

#pragma unroll
        for (int mt = 0; mt < 4; ++mt)
#pragma unroll
            for (int nt = 0; nt < 2; ++nt) {
                u16 pk[4];
#pragma unroll
                for (int r = 0; r < 4; ++r) {
                    float p = __expf(s[mt][nt][r] - 12.0f) *
                              reinterpret_cast<const float*>(&wf[mt])[r];
                    l_acc[nt] += p;
                    pk[r] = f2bf(p);
                }
                uint2 packed;
                packed.x = (unsigned)pk[0] | ((unsigned)pk[1] << 16);
                packed.y = (unsigned)pk[2] | ((unsigned)pk[3] << 16);
                *reinterpret_cast<uint2*>(
                    &p_s[(nt * 16 + l15) * 68 + mt * 16 + quad * 4]) = packed;
            }

#pragma unroll
        for (int mt = 0; mt < 4; ++mt)
            wf[mt] = *reinterpret_cast<const float4*>(wb + ktn * 64 + mt * 16 + quad * 4);

        bf16x8 pa[2][2];
#pragma unroll
        for (int m2 = 0; m2 < 2; ++m2)
#pragma unroll
            for (int h = 0; h < 2; ++h) {
                uint2 lo = *reinterpret_cast<const uint2*>(
                    &p_s[(m2 * 16 + l15) * 68 + h * 32 + quad * 8]);
                uint2 hi = *reinterpret_cast<const uint2*>(
                    &p_s[(m2 * 16 + l15) * 68 + h * 32 + quad * 8 + 4]);
                uint4 c4; c4.x = lo.x; c4.y = lo.y; c4.z = hi.x; c4.w = hi.y;
                pa[m2][h] = __builtin_bit_cast(bf16x8, c4);
            }

#pragma unroll
        for (int m2 = 0; m2 < 2; ++m2)
#pragma unroll
            for (int f = 0; f < 4; ++f) {
                o[m2][f] = __builtin_amdgcn_mfma_f32_16x16x32_bf16(
                    pa[m2][0], __builtin_bit_cast(bf16x8, vf[f][0]), o[m2][f], 0, 0, 0);
                o[m2][f] = __builtin_amdgcn_mfma_f32_16x16x32_bf16(
                    pa[m2][1], __builtin_bit_cast(bf16x8, vf[f][1]), o[m2][f], 0, 0, 0);
            }
    }

    const size_t pbase = (size_t)blockIdx.x * 64;
#pragma unroll
    for (int nt = 0; nt < 2; ++nt) {
        float v = l_acc[nt];
        v += __shfl_xor(v, 16);
        v += __shfl_xor(v, 32);
        if (lane < 16) l_part[pbase + wv * 32 + nt * 16 + lane] = v;
    }
#pragma unroll
    for (int m2 = 0; m2 < 2; ++m2)
#pragma unroll
        for (int f = 0; f < 4; ++f)
#pragma unroll
            for (int r = 0; r < 4; ++r)
                O_part[(pbase + wv * 32 + m2 * 16 + quad * 4 + r) * 64 + f * 16 + l15] =
                    f2bf(o[m2][f][r]);
}

// ---------------------------------------------------------------- combine --
// grid 256: sum 4 split-partials (64 q rows each), normalize, gamma*O+x, transpose
__global__ __launch_bounds__(256) void combine_kernel(
    const u16* __restrict__ O_part, const float* __restrict__ l_part,
    const float* __restrict__ x, const float* __restrict__ g_gamma,
    float* __restrict__ out)
{
    __shared__ float ot[64 * 67];
    __shared__ float ls[64];
    const int t = threadIdx.x;
    const int b = blockIdx.x >> 6;
    const int n0c = (blockIdx.x & 63) << 6;
    const float gamma = g_gamma[0];

    const int r = t >> 2, seg = t & 3;
    float acc[16];
#pragma unroll
    for (int i = 0; i < 16; ++i) acc[i] = 0.f;
#pragma unroll
    for (int s4 = 0; s4 < 4; ++s4) {
        const u16* p = O_part + (((size_t)blockIdx.x * 4 + s4) * 64 + r) * 64 + seg * 16;
        uint4 u0 = *reinterpret_cast<const uint4*>(p);
        uint4 u1 = *reinterpret_cast<const uint4*>(p + 8);
        const unsigned* uu0 = reinterpret_cast<const unsigned*>(&u0);
        const unsigned* uu1 = reinterpret_cast<const unsigned*>(&u1);
#pragma unroll
        for (int i = 0; i < 4; ++i) {
            acc[2 * i]         += bf2f((u16)(uu0[i] & 0xFFFF));
            acc[2 * i + 1]     += bf2f((u16)(uu0[i] >> 16));
            acc[8 + 2 * i]     += bf2f((u16)(uu1[i] & 0xFFFF));
            acc[8 + 2 * i + 1] += bf2f((u16)(uu1[i] >> 16));
        }
    }
#pragma unroll
    for (int i = 0; i < 16; ++i) ot[r * 67 + seg * 16 + i] = acc[i];
    if (seg == 0) {
        float lsum = 0.f;
#pragma unroll
        for (int s4 = 0; s4 < 4; ++s4)
            lsum += l_part[((size_t)blockIdx.x * 4 + s4) * 64 + r];
        ls[r] = gamma / fmaxf(lsum, 1e-30f);
    }
    __syncthreads();
    const int c = t >> 2, chk = t & 3;
    const size_t gbase = ((size_t)(b * 64 + c)) * 4096 + n0c + chk * 16;
#pragma unroll
    for (int j = 0; j < 4; ++j) {
        float4 xv = *reinterpret_cast<const float4*>(&x[gbase + j * 4]);
        float4 rv;
        int nl = chk * 16 + j * 4;
        rv.x = ot[(nl + 0) * 67 + c] * ls[nl + 0] + xv.x;
        rv.y = ot[(nl + 1) * 67 + c] * ls[nl + 1] + xv.y;
        rv.z = ot[(nl + 2) * 67 + c] * ls[nl + 2] + xv.z;
        rv.w = ot[(nl + 3) * 67 + c] * ls[nl + 3] + xv.w;
        *reinterpret_cast<float4*>(&out[gbase + j * 4]) = rv;
    }
}

// ---------------------------------------------------------------- launch ---
extern "C" void kernel_launch(void* const* d_in, const int* in_sizes, int n_in,
                              void* d_out, int out_size, void* d_ws, size_t ws_size,
                              hipStream_t stream) {
    const float* x      = (const float*)d_in[0];
    const float* Wq     = (const float*)d_in[1];
    const float* bq     = (const float*)d_in[2];
    const float* Wk     = (const float*)d_in[3];
    const float* bk     = (const float*)d_in[4];
    const float* Wv     = (const float*)d_in[5];
    const float* bv     = (const float*)d_in[6];
    const float* We1    = (const float*)d_in[7];
    const float* be1    = (const float*)d_in[8];
    const float* bn_w   = (const float*)d_in[9];
    const float* bn_b   = (const float*)d_in[10];
    const float* bn_mean= (const float*)d_in[11];
    const float* bn_var = (const float*)d_in[12];
    const float* We2    = (const float*)d_in[13];
    const float* be2    = (const float*)d_in[14];
    const float* gamma  = (const float*)d_in[15];
    const float* beta   = (const float*)d_in[16];

    char* ws = (char*)d_ws;
    const size_t KB = 1024, MB = 1024 * 1024;
    u16*   Qt     = (u16*)ws;                         // [0, 2 MB)
    u16*   Kt     = (u16*)(ws + 2 * MB);              // [2, 4 MB)
    u16*   Vm     = (u16*)(ws + 4 * MB);              // [4, 6 MB)
    float* wkey   = (float*)(ws + 6 * MB);            // 64 KB
    float* l_part = (float*)(ws + 6 * MB + 64 * KB);  // 256 KB
    u16*   O_part = (u16*)(ws + 6 * MB + 320 * KB);   // 1024*64*64*2 = 8.39 MB

    float* out = (float*)d_out;

    qkv_edge_kernel<<<dim3(512), dim3(256), 0, stream>>>(
        x, Wq, bq, Wk, bk, Wv, bv, We1, be1, bn_w, bn_b, bn_mean, bn_var,
        We2, be2, beta, Qt, Kt, Vm, wkey);
    attn_kernel<<<dim3(1024), dim3(128), 0, stream>>>(Qt, Kt, Vm, wkey, O_part, l_part);
    combine_kernel<<<dim3(256), dim3(256), 0, stream>>>(O_part, l_part, x, gamma, out);
}